// Round 9
// baseline (203.187 us; speedup 1.0000x reference)
//
#include <hip/hip_runtime.h>
#include <hip/hip_bf16.h>

// Attention block: x[2,2048,1024] @ w_qkv^T -> split heads (H=16, Hd=64) ->
// causal softmax attention -> @ w_out^T.
// Device dtypes: inputs FLOAT32, output FLOAT32. Internally bf16 MFMA + f32 acc.
// Pipeline: cvt_all (f32->bf16, fused) -> gemm_nt<1> (QKV proj; Q,K to
// [bh,L,64], V TRANSPOSED to [bh,64,L]) -> attn_fwd8 (flash, 8 waves/block,
// 128 q-rows share K/V staging, double-buffered, peeled causal diagonal,
// shfl-free softmax common path, __expf) -> gemm_nt<0> (out proj -> f32).

typedef __bf16 bf16;
typedef __bf16 bf16x8 __attribute__((ext_vector_type(8)));
typedef __bf16 bf16x4 __attribute__((ext_vector_type(4)));
typedef float  f32x4  __attribute__((ext_vector_type(4)));

#define MFMA16(a, b, c) __builtin_amdgcn_mfma_f32_16x16x32_bf16(a, b, c, 0, 0, 0)

// Fused f32->bf16 convert. Destinations are contiguous in d_ws:
// xb (1048576 float4) | wqkvb (786432) | woutb (262144).
__global__ __launch_bounds__(256) void cvt_all(
    const float* __restrict__ x, const float* __restrict__ wq,
    const float* __restrict__ wo, bf16* __restrict__ dst) {
  int i = blockIdx.x * 256 + threadIdx.x;  // float4 index, grid covers exactly
  const float* src;
  int off;
  if (i < 1048576) {
    src = x; off = i;
  } else if (i < 1048576 + 786432) {
    src = wq; off = i - 1048576;
  } else {
    src = wo; off = i - (1048576 + 786432);
  }
  float4 v = ((const float4*)src)[off];
  bf16x4 o;
  o[0] = (bf16)v.x; o[1] = (bf16)v.y; o[2] = (bf16)v.z; o[3] = (bf16)v.w;
  ((bf16x4*)dst)[i] = o;
}

__device__ __forceinline__ void gload_lds16(const bf16* g, bf16* l) {
  __builtin_amdgcn_global_load_lds(
      (const __attribute__((address_space(1))) void*)g,
      (__attribute__((address_space(3))) void*)l, 16, 0, 0);
}

// Stage a ROWS x 64 bf16 tile into LDS with the XOR slot swizzle applied on
// the GLOBAL source side (global_load_lds writes linearly: base + lane*16).
// 256-thread version (GEMM).
template <int ROWS>
__device__ __forceinline__ void stage_tile(const bf16* __restrict__ src, int ld,
                                           bf16* lds, int tid) {
  const int wid = tid >> 6;
#pragma unroll
  for (int i = 0; i < ROWS / 32; ++i) {
    int c = i * 256 + tid;              // 16B chunk index
    int row = c >> 3;
    int slot = (c & 7) ^ (row & 7);     // pre-swizzled source slot
    gload_lds16(src + row * ld + slot * 8, lds + i * 2048 + wid * 512);
  }
}

// 512-thread version: one 16B chunk per thread covers a 64x64 tile.
__device__ __forceinline__ void stage_tile512(const bf16* __restrict__ src,
                                              int ld, bf16* lds, int tid) {
  int row = tid >> 3;
  int slot = (tid & 7) ^ (row & 7);
  gload_lds16(src + row * ld + slot * 8, lds + (tid >> 6) * 512);
}

// Read 8 contiguous bf16 of tile[row][kbyte/2 ..] with the XOR un-swizzle.
__device__ __forceinline__ bf16x8 read_swz(const bf16* lds, int row, int kbyte) {
  int byte = row * 128 + (kbyte ^ ((row & 7) << 4));
  return *(const bf16x8*)((const char*)lds + byte);
}

// C[m,n] = sum_k A[m,k] * Bt[n,k].  128x128 tile, BK=64, 4 waves in 2x2,
// each wave 64x64 (4x4 fragments of 16x16), mfma_f32_16x16x32_bf16.
// MODE 0: Cf row-major [M,N] FLOAT32.
// MODE 1: QKV scatter: Q,K -> C0/C1 [bh,2048,64] bf16; V -> C2 TRANSPOSED
//         [bh,64,2048] bf16 (so attention stages V^T directly).
template <int MODE>
__global__ __launch_bounds__(256) void gemm_nt(
    const bf16* __restrict__ A, const bf16* __restrict__ Bt,
    bf16* __restrict__ C0, bf16* __restrict__ C1, bf16* __restrict__ C2,
    float* __restrict__ Cf,
    int M, int N, int K, int nbm) {
  __shared__ bf16 ldsA[128 * 64];
  __shared__ bf16 ldsB[128 * 64];
  const int tid = threadIdx.x;
  const int lane = tid & 63, wid = tid >> 6;
  const int wr = wid >> 1, wc = wid & 1;
  const int bm = blockIdx.x % nbm, bn = blockIdx.x / nbm;
  const int l15 = lane & 15, g = lane >> 4;

  f32x4 acc[4][4] = {};
  const bf16* Ab = A + (size_t)bm * 128 * K;
  const bf16* Bb = Bt + (size_t)bn * 128 * K;

  for (int k0 = 0; k0 < K; k0 += 64) {
    __syncthreads();  // protect LDS from previous iteration's readers
    stage_tile<128>(Ab + k0, K, ldsA, tid);
    stage_tile<128>(Bb + k0, K, ldsB, tid);
    __syncthreads();  // drains vmcnt (compiler emits full waitcnt before barrier)
#pragma unroll
    for (int kc = 0; kc < 2; ++kc) {
      bf16x8 af[4], bfr[4];
#pragma unroll
      for (int mi = 0; mi < 4; ++mi)
        af[mi] = read_swz(ldsA, wr * 64 + mi * 16 + l15, kc * 64 + g * 16);
#pragma unroll
      for (int ni = 0; ni < 4; ++ni)
        bfr[ni] = read_swz(ldsB, wc * 64 + ni * 16 + l15, kc * 64 + g * 16);
#pragma unroll
      for (int mi = 0; mi < 4; ++mi)
#pragma unroll
        for (int ni = 0; ni < 4; ++ni)
          acc[mi][ni] = MFMA16(af[mi], bfr[ni], acc[mi][ni]);
    }
  }

  const int mbase = bm * 128 + wr * 64, nbase = bn * 128 + wc * 64;
#pragma unroll
  for (int mi = 0; mi < 4; ++mi) {
#pragma unroll
    for (int ni = 0; ni < 4; ++ni) {
#pragma unroll
      for (int r = 0; r < 4; ++r) {
        // D layout (m89-verified): col = lane&15, row = (lane>>4)*4 + r
        int m = mbase + mi * 16 + g * 4 + r;
        int n = nbase + ni * 16 + l15;
        if (MODE == 0) {
          Cf[(size_t)m * N + n] = acc[mi][ni][r];   // f32 output
        } else {
          bf16 v = (bf16)acc[mi][ni][r];
          int part = n >> 10;               // 0:Q 1:K 2:V
          int hh = (n >> 6) & 15, hd = n & 63;
          int bb = m >> 11, ll = m & 2047;
          size_t bhb = (size_t)(bb * 16 + hh);
          if (part == 2) {
            C2[(bhb * 64 + hd) * 2048 + ll] = v;          // V^T [bh][d][L]
          } else {
            bf16* dst = (part == 0) ? C0 : C1;
            dst[(bhb * 2048 + ll) * 64 + hd] = v;         // [bh][L][d]
          }
        }
      }
    }
  }
}

// Causal flash attention. Q/K: [bh, 2048, 64] bf16; Vt: [bh, 64, 2048] bf16.
// O2: [B*L, 1024] bf16 (head dim h*64+d within row -> out-proj is plain NT).
// Block: 512 threads = 8 waves covering 128 q-rows (two 64-row q-tiles that
// SHARE the K/V staging stream: waves 0-3 = tile A rows, 4-7 = tile B rows).
// Swapped QK^T: S^T = mfma(K_frag, Q_frag) so lane (q = lane&15) holds S
// values for its own q-row. Softmax common path is shfl-free:
// __all(lane_local_max <= m_run) == "row max <= m_run" for every row; the
// true row max (2 shfls) is only computed inside the rare rescale branch.
// Double-buffered staging; A-waves skip the final fully-masked tile (still
// hitting barriers); LPT dispatch (qpair descending).
__global__ __launch_bounds__(512) void attn_fwd8(
    const bf16* __restrict__ Q, const bf16* __restrict__ Kb,
    const bf16* __restrict__ Vt, bf16* __restrict__ O2) {
  __shared__ bf16 ldsK[2][64 * 64];    // swizzled K tiles [64 kv][64 d]  16 KB
  __shared__ bf16 ldsVt[2][64 * 64];   // swizzled V^T tiles [64 d][64 kv] 16 KB
  __shared__ bf16 ldsP[8 * 1024];      // per-wave P [16 q][64 kv], swizzled 16 KB

  const int tid = threadIdx.x, lane = tid & 63, wid = tid >> 6;
  const int l15 = lane & 15, g = lane >> 4;
  const int wsub = wid & 3;            // 16-row group within the wave's q-tile
  const int half = wid >> 2;           // 0 = tile A, 1 = tile B
  const int qpair = 15 - (blockIdx.x >> 5);  // LPT: longest blocks first
  const int bh = blockIdx.x & 31;
  const int b = bh >> 4, h = bh & 15;
  const bf16* Qh  = Q  + (size_t)bh * 2048 * 64;
  const bf16* Kh  = Kb + (size_t)bh * 2048 * 64;
  const bf16* VtH = Vt + (size_t)bh * 64 * 2048;
  const int qbase = qpair * 128;
  const int qrow = qbase + half * 64 + wsub * 16 + l15;  // this lane's q row
  const int myqt = 2 * qpair + half;   // wave's diagonal kv-tile index
  const int nt = 2 * qpair + 2;        // kv tiles processed by this block

  // Loop-invariant swizzled LDS byte offsets (rule #20-safe: const indices).
  int off_rd[4][2];                    // [row-subblock][64B-half] for K/Vt/P
#pragma unroll
  for (int r4 = 0; r4 < 4; ++r4)
#pragma unroll
    for (int dk = 0; dk < 2; ++dk)
      off_rd[r4][dk] = (r4 * 16 + l15) * 128 +
                       ((dk * 64 + g * 16) ^ ((l15 & 7) << 4));
  int off_pw[4];                       // P-write offsets per kv-subblock
#pragma unroll
  for (int s4 = 0; s4 < 4; ++s4)
    off_pw[s4] = l15 * 128 + ((s4 * 32 + g * 8) ^ ((l15 & 7) << 4));
  char* Pw = (char*)&ldsP[wid * 1024];

  // Q fragment (B operand): lane holds Q[qrow][dk*32 + g*8 + j], direct global.
  bf16x8 qf[2];
#pragma unroll
  for (int dk = 0; dk < 2; ++dk)
    qf[dk] = *(const bf16x8*)(Qh + (size_t)qrow * 64 + dk * 32 + g * 8);

  float m_run = -__builtin_inff();
  float l_lane = 0.f;                  // per-lane partial of softmax denom
  f32x4 oacc[4] = {};  // O^T[d = dsub*16 + g*4 + r][q = l15]

  auto step = [&](bool masked, const char* Kt, const char* Vtt) {
    // S^T: A = K[16kv,32d], B = Q -> D[kvloc = g*4+r][q = l15]  (raw logits)
    f32x4 s[4] = {};
#pragma unroll
    for (int sub = 0; sub < 4; ++sub) {
#pragma unroll
      for (int dk = 0; dk < 2; ++dk) {
        bf16x8 kf = *(const bf16x8*)(Kt + off_rd[sub][dk]);
        s[sub] = MFMA16(kf, qf[dk], s[sub]);
      }
    }
    if (masked) {
#pragma unroll
      for (int sub = 0; sub < 4; ++sub)
#pragma unroll
        for (int r = 0; r < 4; ++r) {
          int kvl = sub * 16 + g * 4 + r;          // kv local to tile
          if (kvl > wsub * 16 + l15) s[sub][r] = -__builtin_inff();
        }
    }
    // lane-local max, max3-shaped tree (8 ops)
    float a0 = fmaxf(fmaxf(s[0][0], s[0][1]), s[0][2]);
    float a1 = fmaxf(fmaxf(s[0][3], s[1][0]), s[1][1]);
    float a2 = fmaxf(fmaxf(s[1][2], s[1][3]), s[2][0]);
    float a3 = fmaxf(fmaxf(s[2][1], s[2][2]), s[2][3]);
    float a4 = fmaxf(fmaxf(s[3][0], s[3][1]), s[3][2]);
    float lmax = fmaxf(fmaxf(fmaxf(a0, a1), fmaxf(a2, a3)),
                       fmaxf(a4, s[3][3]));
    // row max <= m_run for ALL rows  <=>  lane max <= m_run for ALL lanes.
    if (!__all(lmax <= m_run)) {       // rare after the first few tiles
      float mt = fmaxf(lmax, __shfl_xor(lmax, 16));
      mt = fmaxf(mt, __shfl_xor(mt, 32));          // row-uniform true max
      float mnew = fmaxf(m_run, mt);
      float alpha = __expf(0.125f * (m_run - mnew));  // first tile: 0
#pragma unroll
      for (int dsub = 0; dsub < 4; ++dsub) {
        oacc[dsub][0] *= alpha; oacc[dsub][1] *= alpha;
        oacc[dsub][2] *= alpha; oacc[dsub][3] *= alpha;
      }
      l_lane *= alpha;
      m_run = mnew;
    }
    const float nms = -0.125f * m_run; // finite by here (first tile rescales)
    float ls[4];
#pragma unroll
    for (int sub = 0; sub < 4; ++sub) {
      bf16x4 pb;
      float e0 = __expf(__builtin_fmaf(s[sub][0], 0.125f, nms));
      float e1 = __expf(__builtin_fmaf(s[sub][1], 0.125f, nms));
      float e2 = __expf(__builtin_fmaf(s[sub][2], 0.125f, nms));
      float e3 = __expf(__builtin_fmaf(s[sub][3], 0.125f, nms));
      pb[0] = (bf16)e0; pb[1] = (bf16)e1; pb[2] = (bf16)e2; pb[3] = (bf16)e3;
      ls[sub] = (e0 + e1) + (e2 + e3);
      *(bf16x4*)(Pw + off_pw[sub]) = pb;
    }
    l_lane += (ls[0] + ls[1]) + (ls[2] + ls[3]);
    // PV: O^T += V^T * P^T  (A = Vt frag rows=d, B = P^T frag, both swizzled)
#pragma unroll
    for (int kc = 0; kc < 2; ++kc) {
      bf16x8 pf = *(const bf16x8*)(Pw + off_rd[0][kc]);
#pragma unroll
      for (int dsub = 0; dsub < 4; ++dsub) {
        bf16x8 vf = *(const bf16x8*)(Vtt + off_rd[dsub][kc]);
        oacc[dsub] = MFMA16(vf, pf, oacc[dsub]);
      }
    }
  };

  // prologue: stage tile 0 into buffer 0
  stage_tile512(Kh, 64, &ldsK[0][0], tid);
  stage_tile512(VtH, 2048, &ldsVt[0][0], tid);
  __syncthreads();

  int cur = 0;
  for (int t = 0; t < nt; ++t) {
    if (t + 1 < nt) {                  // prefetch next tile (in flight during compute)
      stage_tile512(Kh + (size_t)(t + 1) * 64 * 64, 64, &ldsK[cur ^ 1][0], tid);
      stage_tile512(VtH + (t + 1) * 64, 2048, &ldsVt[cur ^ 1][0], tid);
    }
    if (t <= myqt)                     // A-waves skip the final (fully masked) tile
      step(t == myqt, (const char*)&ldsK[cur][0], (const char*)&ldsVt[cur][0]);
    __syncthreads();                   // staging drained + all waves done reading
    cur ^= 1;
  }

  float l_run = l_lane;
  l_run += __shfl_xor(l_run, 16);
  l_run += __shfl_xor(l_run, 32);
  const float linv = 1.f / l_run;
#pragma unroll
  for (int dsub = 0; dsub < 4; ++dsub)
#pragma unroll
    for (int r = 0; r < 4; ++r) {
      int d = dsub * 16 + g * 4 + r;
      O2[((size_t)(b * 2048 + qrow)) * 1024 + h * 64 + d] =
          (bf16)(oacc[dsub][r] * linv);
    }
}

extern "C" void kernel_launch(void* const* d_in, const int* in_sizes, int n_in,
                              void* d_out, int out_size, void* d_ws, size_t ws_size,
                              hipStream_t stream) {
  const float* x     = (const float*)d_in[0];   // [2,2048,1024] f32
  // d_in[1] = causal mask: known tril, not read
  const float* w_qkv = (const float*)d_in[2];   // [3072,1024] f32
  const float* w_out = (const float*)d_in[3];   // [1024,1024] f32
  float* out = (float*)d_out;                   // [2,2048,1024] f32

  char* ws = (char*)d_ws;
  bf16* xb    = (bf16*)(ws);                        // [4096,1024]   8 MiB
  bf16* wqkvb = (bf16*)(ws + ((size_t)8 << 20));    // [3072,1024]   6 MiB
  bf16* woutb = (bf16*)(ws + ((size_t)14 << 20));   // [1024,1024]   2 MiB
  bf16* Qb    = (bf16*)(ws + ((size_t)16 << 20));   // [32,2048,64]  8 MiB
  bf16* Kbuf  = (bf16*)(ws + ((size_t)24 << 20));   // [32,2048,64]  8 MiB
  bf16* Vtb   = (bf16*)(ws + ((size_t)32 << 20));   // [32,64,2048]  8 MiB (V^T)
  bf16* O2    = (bf16*)(ws + ((size_t)40 << 20));   // [4096,1024]   8 MiB

  // fused f32 -> bf16 conversion (dst regions contiguous at ws base)
  cvt_all<<<dim3(8192), 256, 0, stream>>>(x, w_qkv, w_out, xb);

  // QKV projection: M=4096, N=3072, K=1024 (V stored transposed)
  gemm_nt<1><<<dim3(32 * 24), 256, 0, stream>>>(xb, wqkvb, Qb, Kbuf, Vtb,
                                                nullptr, 4096, 3072, 1024, 32);
  // Flash attention: 512 blocks (32 bh x 16 q-pairs), 8 waves each
  attn_fwd8<<<dim3(32 * 16), 512, 0, stream>>>(Qb, Kbuf, Vtb, O2);
  // Output projection: M=4096, N=1024, K=1024 -> f32 out
  gemm_nt<0><<<dim3(32 * 8), 256, 0, stream>>>(O2, woutb, nullptr, nullptr,
                                               nullptr, out, 4096, 1024, 1024, 32);
}

// Round 12
// 202.727 us; speedup vs baseline: 1.0023x; 1.0023x over previous
//
#include <hip/hip_runtime.h>
#include <hip/hip_bf16.h>

// Attention block: x[2,2048,1024] @ w_qkv^T -> split heads (H=16, Hd=64) ->
// causal softmax attention -> @ w_out^T.
// Device dtypes: inputs FLOAT32, output FLOAT32. Internally bf16 MFMA + f32 acc.
// Pipeline: cvt_all -> gemm_nt<1> (QKV; V stored transposed) -> attn_fwd8
// (flash, KVBLK=128, rotated subtile order to de-phase waves, setprio,
// balanced block pairing) -> gemm_nt<0> (out proj -> f32 d_out).

typedef __bf16 bf16;
typedef __bf16 bf16x8 __attribute__((ext_vector_type(8)));
typedef __bf16 bf16x4 __attribute__((ext_vector_type(4)));
typedef float  f32x4  __attribute__((ext_vector_type(4)));

#define MFMA16(a, b, c) __builtin_amdgcn_mfma_f32_16x16x32_bf16(a, b, c, 0, 0, 0)

// Fused f32->bf16 convert. Destinations are contiguous in d_ws:
// xb (1048576 float4) | wqkvb (786432) | woutb (262144).
__global__ __launch_bounds__(256) void cvt_all(
    const float* __restrict__ x, const float* __restrict__ wq,
    const float* __restrict__ wo, bf16* __restrict__ dst) {
  int i = blockIdx.x * 256 + threadIdx.x;  // float4 index, grid covers exactly
  const float* src;
  int off;
  if (i < 1048576) {
    src = x; off = i;
  } else if (i < 1048576 + 786432) {
    src = wq; off = i - 1048576;
  } else {
    src = wo; off = i - (1048576 + 786432);
  }
  float4 v = ((const float4*)src)[off];
  bf16x4 o;
  o[0] = (bf16)v.x; o[1] = (bf16)v.y; o[2] = (bf16)v.z; o[3] = (bf16)v.w;
  ((bf16x4*)dst)[i] = o;
}

__device__ __forceinline__ void gload_lds16(const bf16* g, bf16* l) {
  __builtin_amdgcn_global_load_lds(
      (const __attribute__((address_space(1))) void*)g,
      (__attribute__((address_space(3))) void*)l, 16, 0, 0);
}

// GEMM staging: ROWS x 64 tile, 256 threads, XOR slot swizzle on the GLOBAL
// source side (global_load_lds writes linearly: wave base + lane*16).
template <int ROWS>
__device__ __forceinline__ void stage_tile(const bf16* __restrict__ src, int ld,
                                           bf16* lds, int tid) {
  const int wid = tid >> 6;
#pragma unroll
  for (int i = 0; i < ROWS / 32; ++i) {
    int c = i * 256 + tid;              // 16B chunk index
    int row = c >> 3;
    int slot = (c & 7) ^ (row & 7);     // pre-swizzled source slot
    gload_lds16(src + row * ld + slot * 8, lds + i * 2048 + wid * 512);
  }
}

// Attention staging: 1024-chunk (16KB) tile, 512 threads, 2 chunks/thread.
// LOG2C = log2(16B-chunks per row). Swizzle: slot ^= (row & 7).
template <int LOG2C>
__device__ __forceinline__ void stage2_512(const bf16* __restrict__ src, int ld,
                                           bf16* lds, int tid) {
#pragma unroll
  for (int i = 0; i < 2; ++i) {
    int c = i * 512 + tid;
    int row = c >> LOG2C;
    int slot = (c & ((1 << LOG2C) - 1)) ^ (row & 7);
    gload_lds16(src + row * ld + slot * 8, lds + i * 4096 + (tid >> 6) * 512);
  }
}

// Read 8 contiguous bf16 of a [*][64] tile row with the XOR un-swizzle.
__device__ __forceinline__ bf16x8 read_swz(const bf16* lds, int row, int kbyte) {
  int byte = row * 128 + (kbyte ^ ((row & 7) << 4));
  return *(const bf16x8*)((const char*)lds + byte);
}

// C[m,n] = sum_k A[m,k] * Bt[n,k].  128x128 tile, BK=64, 4 waves in 2x2,
// each wave 64x64 (4x4 fragments of 16x16), mfma_f32_16x16x32_bf16.
// MODE 0: Cf row-major [M,N] FLOAT32.
// MODE 1: QKV scatter: Q,K -> C0/C1 [bh,2048,64] bf16; V -> C2 TRANSPOSED
//         [bh,64,2048] bf16 (so attention stages V^T directly).
template <int MODE>
__global__ __launch_bounds__(256) void gemm_nt(
    const bf16* __restrict__ A, const bf16* __restrict__ Bt,
    bf16* __restrict__ C0, bf16* __restrict__ C1, bf16* __restrict__ C2,
    float* __restrict__ Cf,
    int M, int N, int K, int nbm) {
  __shared__ bf16 ldsA[128 * 64];
  __shared__ bf16 ldsB[128 * 64];
  const int tid = threadIdx.x;
  const int lane = tid & 63, wid = tid >> 6;
  const int wr = wid >> 1, wc = wid & 1;
  const int bm = blockIdx.x % nbm, bn = blockIdx.x / nbm;
  const int l15 = lane & 15, g = lane >> 4;

  f32x4 acc[4][4] = {};
  const bf16* Ab = A + (size_t)bm * 128 * K;
  const bf16* Bb = Bt + (size_t)bn * 128 * K;

  for (int k0 = 0; k0 < K; k0 += 64) {
    __syncthreads();  // protect LDS from previous iteration's readers
    stage_tile<128>(Ab + k0, K, ldsA, tid);
    stage_tile<128>(Bb + k0, K, ldsB, tid);
    __syncthreads();  // drains vmcnt (compiler emits full waitcnt before barrier)
#pragma unroll
    for (int kc = 0; kc < 2; ++kc) {
      bf16x8 af[4], bfr[4];
#pragma unroll
      for (int mi = 0; mi < 4; ++mi)
        af[mi] = read_swz(ldsA, wr * 64 + mi * 16 + l15, kc * 64 + g * 16);
#pragma unroll
      for (int ni = 0; ni < 4; ++ni)
        bfr[ni] = read_swz(ldsB, wc * 64 + ni * 16 + l15, kc * 64 + g * 16);
#pragma unroll
      for (int mi = 0; mi < 4; ++mi)
#pragma unroll
        for (int ni = 0; ni < 4; ++ni)
          acc[mi][ni] = MFMA16(af[mi], bfr[ni], acc[mi][ni]);
    }
  }

  const int mbase = bm * 128 + wr * 64, nbase = bn * 128 + wc * 64;
#pragma unroll
  for (int mi = 0; mi < 4; ++mi) {
#pragma unroll
    for (int ni = 0; ni < 4; ++ni) {
#pragma unroll
      for (int r = 0; r < 4; ++r) {
        // D layout (m89-verified): col = lane&15, row = (lane>>4)*4 + r
        int m = mbase + mi * 16 + g * 4 + r;
        int n = nbase + ni * 16 + l15;
        if (MODE == 0) {
          Cf[(size_t)m * N + n] = acc[mi][ni][r];   // f32 output
        } else {
          bf16 v = (bf16)acc[mi][ni][r];
          int part = n >> 10;               // 0:Q 1:K 2:V
          int hh = (n >> 6) & 15, hd = n & 63;
          int bb = m >> 11, ll = m & 2047;
          size_t bhb = (size_t)(bb * 16 + hh);
          if (part == 2) {
            C2[(bhb * 64 + hd) * 2048 + ll] = v;          // V^T [bh][d][L]
          } else {
            bf16* dst = (part == 0) ? C0 : C1;
            dst[(bhb * 2048 + ll) * 64 + hd] = v;         // [bh][L][d]
          }
        }
      }
    }
  }
}

// Causal flash attention. Q/K: [bh, 2048, 64] bf16; Vt: [bh, 64, 2048] bf16.
// O2: [B*L, 1024] bf16. Block: 512 threads = 8 waves covering 128 q-rows
// (waves 0-3 = rows 0-63 "A", waves 4-7 = rows 64-127 "B"), sharing a
// KVBLK=128 double-buffered K/Vt staging stream (halves barrier count vs 64).
// Each 128-kv tile = two 64-kv subtiles; waves process them in ROTATED order
// (wid&1) so softmax-VALU of one wave group overlaps MFMA/LDS of the other
// (breaks the barrier convoy). Swapped QK^T (lane l15 owns its q-row's S).
// Softmax common path is shfl-free; setprio(1) wraps MFMA clusters.
// Final tile: A-waves do only subtile 0 (diag-masked); B-waves do subtile 0
// unmasked + subtile 1 diag-masked.
__global__ __launch_bounds__(512) void attn_fwd8(
    const bf16* __restrict__ Q, const bf16* __restrict__ Kb,
    const bf16* __restrict__ Vt, bf16* __restrict__ O2) {
  __shared__ bf16 ldsK[2][128 * 64];   // K tiles [128 kv][64 d], swizzled 32 KB
  __shared__ bf16 ldsVt[2][64 * 128];  // V^T tiles [64 d][128 kv], swizzled 32 KB
  __shared__ bf16 ldsP[8][16 * 32];    // per-wave P [16 q][32 kv] (per kc) 8 KB

  const int tid = threadIdx.x, lane = tid & 63, wid = tid >> 6;
  const int l15 = lane & 15, g = lane >> 4;
  const int wsub = wid & 3;            // 16-row group within the 64-row q-tile
  const int hlf = wid >> 2;            // 0 = rows 0-63 (A), 1 = rows 64-127 (B)
  const int bid = blockIdx.x;
  // Balanced pairing: first 256 blocks qpair 15..8, second 256 qpair 0..7
  // (CU's two resident blocks sum to 17 tile-steps).
  const int qpair = (bid < 256) ? (15 - (bid >> 5)) : ((bid >> 5) - 8);
  const int bh = bid & 31;
  const int b = bh >> 4, h = bh & 15;
  const bf16* Qh  = Q  + (size_t)bh * 2048 * 64;
  const bf16* Kh  = Kb + (size_t)bh * 2048 * 64;
  const bf16* VtH = Vt + (size_t)bh * 64 * 2048;
  const int qbase = qpair * 128;
  const int qrow = qbase + hlf * 64 + wsub * 16 + l15;  // this lane's q row
  const int nt = qpair + 1;            // 128-kv tiles processed by this block

  // Loop-invariant swizzled LDS byte offsets.
  int offK[4][2];                      // K frag [kv-sub][d-half]; + s*8192
#pragma unroll
  for (int s4 = 0; s4 < 4; ++s4)
#pragma unroll
    for (int dk = 0; dk < 2; ++dk)
      offK[s4][dk] = (s4 * 16 + l15) * 128 +
                     ((dk * 64 + g * 16) ^ ((l15 & 7) << 4));
  int offV[4][2];                      // Vt frag [d-sub][kc]; + s*128
#pragma unroll
  for (int d4 = 0; d4 < 4; ++d4)
#pragma unroll
    for (int kc = 0; kc < 2; ++kc)
      offV[d4][kc] = (d4 * 16 + l15) * 256 +
                     ((kc * 64 + g * 16) ^ ((l15 & 7) << 4));
  const int offPw0 = l15 * 64 + g * 8;        // P write, j=0 (j=1: +32)
  const int offPr  = l15 * 64 + g * 16;       // P read (B-frag)
  char* Pw = (char*)&ldsP[wid][0];

  // Q fragment (B operand): lane holds Q[qrow][dk*32 + g*8 + j], direct global.
  bf16x8 qf[2];
#pragma unroll
  for (int dk = 0; dk < 2; ++dk)
    qf[dk] = *(const bf16x8*)(Qh + (size_t)qrow * 64 + dk * 32 + g * 8);

  float m_run = -__builtin_inff();
  float l_lane = 0.f;                  // per-lane partial of softmax denom
  f32x4 oacc[4] = {};  // O^T[d = dsub*16 + g*4 + r][q = l15]

  // One 64-kv subtile (s = 0/1 within the 128-kv tile).
  auto sub_step = [&](int s, bool masked, const char* Kt, const char* Vtt) {
    const char* Ks = Kt + s * 8192;
    const char* Vs = Vtt + s * 128;
    f32x4 sv[4] = {};
    __builtin_amdgcn_s_setprio(1);
#pragma unroll
    for (int sub = 0; sub < 4; ++sub) {
#pragma unroll
      for (int dk = 0; dk < 2; ++dk) {
        bf16x8 kf = *(const bf16x8*)(Ks + offK[sub][dk]);
        sv[sub] = MFMA16(kf, qf[dk], sv[sub]);
      }
    }
    __builtin_amdgcn_s_setprio(0);
    if (masked) {
#pragma unroll
      for (int sub = 0; sub < 4; ++sub)
#pragma unroll
        for (int r = 0; r < 4; ++r) {
          int kvl = sub * 16 + g * 4 + r;          // kv local to subtile
          if (kvl > wsub * 16 + l15) sv[sub][r] = -__builtin_inff();
        }
    }
    // lane-local max tree
    float a0 = fmaxf(fmaxf(sv[0][0], sv[0][1]), sv[0][2]);
    float a1 = fmaxf(fmaxf(sv[0][3], sv[1][0]), sv[1][1]);
    float a2 = fmaxf(fmaxf(sv[1][2], sv[1][3]), sv[2][0]);
    float a3 = fmaxf(fmaxf(sv[2][1], sv[2][2]), sv[2][3]);
    float a4 = fmaxf(fmaxf(sv[3][0], sv[3][1]), sv[3][2]);
    float lmax = fmaxf(fmaxf(fmaxf(a0, a1), fmaxf(a2, a3)),
                       fmaxf(a4, sv[3][3]));
    // row max <= m_run for ALL rows  <=>  lane max <= m_run for ALL lanes.
    if (!__all(lmax <= m_run)) {       // rare after the first few subtiles
      float mt = fmaxf(lmax, __shfl_xor(lmax, 16));
      mt = fmaxf(mt, __shfl_xor(mt, 32));          // row-uniform true max
      float mnew = fmaxf(m_run, mt);
      float alpha = __expf(0.125f * (m_run - mnew));  // first subtile: 0
#pragma unroll
      for (int dsub = 0; dsub < 4; ++dsub) {
        oacc[dsub][0] *= alpha; oacc[dsub][1] *= alpha;
        oacc[dsub][2] *= alpha; oacc[dsub][3] *= alpha;
      }
      l_lane *= alpha;
      m_run = mnew;
    }
    const float nms = -0.125f * m_run; // finite (first subtile rescales)
#pragma unroll
    for (int kc = 0; kc < 2; ++kc) {
      float lsq = 0.f;
#pragma unroll
      for (int j = 0; j < 2; ++j) {
        const f32x4& sj = sv[kc * 2 + j];
        float e0 = __expf(__builtin_fmaf(sj[0], 0.125f, nms));
        float e1 = __expf(__builtin_fmaf(sj[1], 0.125f, nms));
        float e2 = __expf(__builtin_fmaf(sj[2], 0.125f, nms));
        float e3 = __expf(__builtin_fmaf(sj[3], 0.125f, nms));
        bf16x4 pb;
        pb[0] = (bf16)e0; pb[1] = (bf16)e1; pb[2] = (bf16)e2; pb[3] = (bf16)e3;
        lsq += (e0 + e1) + (e2 + e3);
        *(bf16x4*)(Pw + offPw0 + j * 32) = pb;
      }
      l_lane += lsq;
      bf16x8 pf = *(const bf16x8*)(Pw + offPr);
      __builtin_amdgcn_s_setprio(1);
#pragma unroll
      for (int dsub = 0; dsub < 4; ++dsub) {
        bf16x8 vf = *(const bf16x8*)(Vs + offV[dsub][kc]);
        oacc[dsub] = MFMA16(vf, pf, oacc[dsub]);
      }
      __builtin_amdgcn_s_setprio(0);
    }
  };

  // prologue: stage tile 0 into buffer 0
  stage2_512<3>(Kh, 64, &ldsK[0][0], tid);
  stage2_512<4>(VtH, 2048, &ldsVt[0][0], tid);
  __syncthreads();

  const int sf = wid & 1;              // rotated subtile order per wave parity
  int cur = 0;
  for (int t = 0; t < nt; ++t) {
    if (t + 1 < nt) {                  // prefetch next 128-kv tile
      stage2_512<3>(Kh + (size_t)(t + 1) * 128 * 64, 64, &ldsK[cur ^ 1][0], tid);
      stage2_512<4>(VtH + (t + 1) * 128, 2048, &ldsVt[cur ^ 1][0], tid);
    }
    const char* Kt  = (const char*)&ldsK[cur][0];
    const char* Vtt = (const char*)&ldsVt[cur][0];
    if (t < nt - 1) {                  // fully unmasked tile
      sub_step(sf, false, Kt, Vtt);
      sub_step(sf ^ 1, false, Kt, Vtt);
    } else if (hlf == 0) {             // A-waves: diagonal in subtile 0 only
      sub_step(0, true, Kt, Vtt);
    } else {                           // B-waves: sub0 unmasked, sub1 diagonal
      sub_step(sf, sf == 1, Kt, Vtt);
      sub_step(sf ^ 1, (sf ^ 1) == 1, Kt, Vtt);
    }
    __syncthreads();                   // staging drained + all waves done reading
    cur ^= 1;
  }

  float l_run = l_lane;
  l_run += __shfl_xor(l_run, 16);
  l_run += __shfl_xor(l_run, 32);
  const float linv = 1.f / l_run;
#pragma unroll
  for (int dsub = 0; dsub < 4; ++dsub)
#pragma unroll
    for (int r = 0; r < 4; ++r) {
      int d = dsub * 16 + g * 4 + r;
      O2[((size_t)(b * 2048 + qrow)) * 1024 + h * 64 + d] =
          (bf16)(oacc[dsub][r] * linv);
    }
}

extern "C" void kernel_launch(void* const* d_in, const int* in_sizes, int n_in,
                              void* d_out, int out_size, void* d_ws, size_t ws_size,
                              hipStream_t stream) {
  const float* x     = (const float*)d_in[0];   // [2,2048,1024] f32
  // d_in[1] = causal mask: known tril, not read
  const float* w_qkv = (const float*)d_in[2];   // [3072,1024] f32
  const float* w_out = (const float*)d_in[3];   // [1024,1024] f32
  float* out = (float*)d_out;                   // [2,2048,1024] f32

  char* ws = (char*)d_ws;
  bf16* xb    = (bf16*)(ws);                        // [4096,1024]   8 MiB
  bf16* wqkvb = (bf16*)(ws + ((size_t)8 << 20));    // [3072,1024]   6 MiB
  bf16* woutb = (bf16*)(ws + ((size_t)14 << 20));   // [1024,1024]   2 MiB
  bf16* Qb    = (bf16*)(ws + ((size_t)16 << 20));   // [32,2048,64]  8 MiB
  bf16* Kbuf  = (bf16*)(ws + ((size_t)24 << 20));   // [32,2048,64]  8 MiB
  bf16* Vtb   = (bf16*)(ws + ((size_t)32 << 20));   // [32,64,2048]  8 MiB (V^T)
  bf16* O2    = (bf16*)(ws + ((size_t)40 << 20));   // [4096,1024]   8 MiB

  // fused f32 -> bf16 conversion (dst regions contiguous at ws base)
  cvt_all<<<dim3(8192), 256, 0, stream>>>(x, w_qkv, w_out, xb);

  // QKV projection: M=4096, N=3072, K=1024 (V stored transposed)
  gemm_nt<1><<<dim3(32 * 24), 256, 0, stream>>>(xb, wqkvb, Qb, Kbuf, Vtb,
                                                nullptr, 4096, 3072, 1024, 32);
  // Flash attention: 512 blocks (balanced long/short pairing), 8 waves each
  attn_fwd8<<<dim3(32 * 16), 512, 0, stream>>>(Qb, Kbuf, Vtb, O2);
  // Output projection: M=4096, N=1024, K=1024 -> f32 out
  gemm_nt<0><<<dim3(32 * 8), 256, 0, stream>>>(O2, woutb, nullptr, nullptr,
                                               nullptr, out, 4096, 1024, 1024, 32);
}